// Round 1
// baseline (1696.767 us; speedup 1.0000x reference)
//
#include <hip/hip_runtime.h>
#include <hip/hip_bf16.h>

typedef __bf16 bf16x8 __attribute__((ext_vector_type(8)));
typedef __bf16 bf16x4 __attribute__((ext_vector_type(4)));
typedef float  f32x4  __attribute__((ext_vector_type(4)));

#define N_NODES  16384
#define N_EDGES  262144
#define N_GRAPHS 16
#define IN_CH    128
#define HID_CH   256
#define LAT      64

// ---------------- init: deg=1 (self loop), zero pooling accumulators ----------------
__global__ __launch_bounds__(256) void k_init(float* __restrict__ deg,
                                              float* __restrict__ gsum,
                                              float* __restrict__ gcnt) {
  int t = blockIdx.x * 256 + threadIdx.x;
  if (t < N_NODES) deg[t] = 1.0f;
  if (t < N_GRAPHS * LAT) gsum[t] = 0.0f;
  if (t < N_GRAPHS) gcnt[t] = 0.0f;
}

__global__ __launch_bounds__(256) void k_deg(const int* __restrict__ col,
                                             float* __restrict__ deg) {
  int e = blockIdx.x * 256 + threadIdx.x;
  atomicAdd(&deg[col[e]], 1.0f);
}

__global__ __launch_bounds__(256) void k_dinv(const float* __restrict__ deg,
                                              float* __restrict__ dinv) {
  int n = blockIdx.x * 256 + threadIdx.x;
  dinv[n] = rsqrtf(deg[n]);
}

// agg[n] = x[n] * dinv[n]^2   (self-loop term; also serves as the zero-init)
__global__ __launch_bounds__(256) void k_selfinit(const float* __restrict__ x,
                                                  const float* __restrict__ dinv,
                                                  float* __restrict__ agg) {
  int t = blockIdx.x * 256 + threadIdx.x;
  int n = t >> 5, c4 = (t & 31) << 2;
  float w = dinv[n]; w *= w;
  float4 xv = *(const float4*)(x + (size_t)n * IN_CH + c4);
  float4 o = make_float4(xv.x * w, xv.y * w, xv.z * w, xv.w * w);
  *(float4*)(agg + (size_t)n * IN_CH + c4) = o;
}

// agg[col] += x[row] * dinv[row]*dinv[col] ; 32 threads per edge, 4 channels each
__global__ __launch_bounds__(256) void k_edge_agg(const int* __restrict__ erow,
                                                  const int* __restrict__ ecol,
                                                  const float* __restrict__ x,
                                                  const float* __restrict__ dinv,
                                                  float* __restrict__ agg) {
  int t = blockIdx.x * 256 + threadIdx.x;
  int e = t >> 5, c4 = (t & 31) << 2;
  int r = erow[e], c = ecol[e];
  float w = dinv[r] * dinv[c];
  float4 xv = *(const float4*)(x + (size_t)r * IN_CH + c4);
  float* dst = agg + (size_t)c * IN_CH + c4;
  atomicAdd(dst + 0, xv.x * w);
  atomicAdd(dst + 1, xv.y * w);
  atomicAdd(dst + 2, xv.z * w);
  atomicAdd(dst + 3, xv.w * w);
}

// ---------------- fp32 NT GEMM: C[m][n] = act(sum_k A[m][k]*B[n][k] + bias[n]) ----------------
// 64x64 tile, 256 threads, 4x4 per thread, BK=32.
template <bool RELU, bool STORE_BF16>
__global__ __launch_bounds__(256) void gemm_nt(const float* __restrict__ A,
                                               const float* __restrict__ B,
                                               const float* __restrict__ bias,
                                               float* __restrict__ C,
                                               __bf16* __restrict__ Cbf,
                                               int M, int N, int K) {
  __shared__ float As[64][33];
  __shared__ float Bs[64][33];
  int tid = threadIdx.x;
  int row0 = blockIdx.y * 64, col0 = blockIdx.x * 64;
  int tx = tid & 15, ty = tid >> 4;
  float acc[4][4] = {};
  int f4 = (tid & 7) * 4, r = tid >> 3;
  for (int k0 = 0; k0 < K; k0 += 32) {
    float4 a0 = *(const float4*)(A + (size_t)(row0 + r) * K + k0 + f4);
    float4 a1 = *(const float4*)(A + (size_t)(row0 + r + 32) * K + k0 + f4);
    float4 b0 = *(const float4*)(B + (size_t)(col0 + r) * K + k0 + f4);
    float4 b1 = *(const float4*)(B + (size_t)(col0 + r + 32) * K + k0 + f4);
    As[r][f4 + 0] = a0.x; As[r][f4 + 1] = a0.y; As[r][f4 + 2] = a0.z; As[r][f4 + 3] = a0.w;
    As[r + 32][f4 + 0] = a1.x; As[r + 32][f4 + 1] = a1.y; As[r + 32][f4 + 2] = a1.z; As[r + 32][f4 + 3] = a1.w;
    Bs[r][f4 + 0] = b0.x; Bs[r][f4 + 1] = b0.y; Bs[r][f4 + 2] = b0.z; Bs[r][f4 + 3] = b0.w;
    Bs[r + 32][f4 + 0] = b1.x; Bs[r + 32][f4 + 1] = b1.y; Bs[r + 32][f4 + 2] = b1.z; Bs[r + 32][f4 + 3] = b1.w;
    __syncthreads();
#pragma unroll
    for (int kk = 0; kk < 32; ++kk) {
      float av[4], bv[4];
#pragma unroll
      for (int i = 0; i < 4; ++i) av[i] = As[ty * 4 + i][kk];
#pragma unroll
      for (int j = 0; j < 4; ++j) bv[j] = Bs[tx * 4 + j][kk];
#pragma unroll
      for (int i = 0; i < 4; ++i)
#pragma unroll
        for (int j = 0; j < 4; ++j) acc[i][j] = fmaf(av[i], bv[j], acc[i][j]);
    }
    __syncthreads();
  }
  float4 bb = *(const float4*)(bias + col0 + tx * 4);
  float bias4[4] = {bb.x, bb.y, bb.z, bb.w};
#pragma unroll
  for (int i = 0; i < 4; ++i) {
    int rw = row0 + ty * 4 + i;
    float o[4];
#pragma unroll
    for (int j = 0; j < 4; ++j) {
      float v = acc[i][j] + bias4[j];
      o[j] = RELU ? fmaxf(v, 0.0f) : v;
    }
    *(float4*)(C + (size_t)rw * N + col0 + tx * 4) = make_float4(o[0], o[1], o[2], o[3]);
    if (STORE_BF16) {
      bf16x4 bv4;
      bv4[0] = (__bf16)o[0]; bv4[1] = (__bf16)o[1];
      bv4[2] = (__bf16)o[2]; bv4[3] = (__bf16)o[3];
      *(bf16x4*)(Cbf + (size_t)rw * N + col0 + tx * 4) = bv4;
    }
  }
}

// ---------------- pooling: batch is sorted -> running segment accumulator ----------------
#define POOL_NODES 64
__global__ __launch_bounds__(64) void k_pool(const float* __restrict__ z,
                                             const int* __restrict__ batch,
                                             float* __restrict__ gsum,
                                             float* __restrict__ gcnt) {
  int c = threadIdx.x;  // channel 0..63
  int n0 = blockIdx.x * POOL_NODES;
  float acc = 0.0f, cnt = 0.0f;
  int g = batch[n0];
  for (int i = 0; i < POOL_NODES; ++i) {
    int n = n0 + i;
    int gn = batch[n];
    if (gn != g) {
      atomicAdd(&gsum[g * LAT + c], acc);
      if (c == 0) atomicAdd(&gcnt[g], cnt);
      acc = 0.0f; cnt = 0.0f; g = gn;
    }
    acc += z[(size_t)n * LAT + c];
    cnt += 1.0f;
  }
  atomicAdd(&gsum[g * LAT + c], acc);
  if (c == 0) atomicAdd(&gcnt[g], cnt);
}

// z_graph = gsum/max(cnt,1); xrow[g][ch] = z_graph[g] . dec_w[ch] + dec_b[ch]
__global__ __launch_bounds__(1024) void k_graph(const float* __restrict__ gsum,
                                                const float* __restrict__ gcnt,
                                                const float* __restrict__ dec_w,
                                                const float* __restrict__ dec_b,
                                                float* __restrict__ zg_out,
                                                float* __restrict__ xrow) {
  __shared__ float zg[N_GRAPHS * LAT];
  int t = threadIdx.x;  // 0..1023
  int g = t >> 6;
  float v = gsum[t] / fmaxf(gcnt[g], 1.0f);
  zg[t] = v;
  zg_out[t] = v;
  __syncthreads();
  for (int i = t; i < N_GRAPHS * IN_CH; i += 1024) {
    int gg = i >> 7, ch = i & 127;
    float s = dec_b[ch];
#pragma unroll
    for (int k = 0; k < LAT; ++k) s += zg[gg * LAT + k] * dec_w[ch * LAT + k];
    xrow[i] = s;
  }
}

__global__ __launch_bounds__(256) void k_xhat(const int* __restrict__ batch,
                                              const float* __restrict__ xrow,
                                              float* __restrict__ xhat) {
  int t = blockIdx.x * 256 + threadIdx.x;
  int n = t >> 5, c4 = (t & 31) << 2;
  int g = batch[n];
  float4 v = *(const float4*)(xrow + (size_t)g * IN_CH + c4);
  *(float4*)(xhat + (size_t)n * IN_CH + c4) = v;
}

// ---------------- a_hat = sigmoid(z z^T) via bf16 MFMA ----------------
// block = 4 waves (2x2), block tile 64 rows x 128 cols, wave tile 32x64 (2x4 of 16x16).
// A frag (16x16x32): A[m=lane&15][k=(lane>>4)*8+j]; B frag: B[k][n=lane&15], k=(lane>>4)*8+j.
// C/D: col=lane&15, row=(lane>>4)*4+reg  [m89-verified]. a_hat symmetric -> robust.
__global__ __launch_bounds__(256) void k_ahat(const __bf16* __restrict__ zb,
                                              float* __restrict__ out) {
  int lane = threadIdx.x & 63;
  int wave = threadIdx.x >> 6;
  int wr = wave >> 1, wc = wave & 1;
  int rowBase = blockIdx.y * 64 + wr * 32;
  int colBase = blockIdx.x * 128 + wc * 64;
  int idx = lane & 15, q = lane >> 4;
  f32x4 acc[2][4] = {};
#pragma unroll
  for (int k0 = 0; k0 < LAT; k0 += 32) {
    bf16x8 a[2], b[4];
#pragma unroll
    for (int t = 0; t < 2; ++t)
      a[t] = *(const bf16x8*)(zb + (size_t)(rowBase + t * 16 + idx) * LAT + k0 + q * 8);
#pragma unroll
    for (int u = 0; u < 4; ++u)
      b[u] = *(const bf16x8*)(zb + (size_t)(colBase + u * 16 + idx) * LAT + k0 + q * 8);
#pragma unroll
    for (int t = 0; t < 2; ++t)
#pragma unroll
      for (int u = 0; u < 4; ++u)
        acc[t][u] = __builtin_amdgcn_mfma_f32_16x16x32_bf16(a[t], b[u], acc[t][u], 0, 0, 0);
  }
#pragma unroll
  for (int t = 0; t < 2; ++t)
#pragma unroll
    for (int u = 0; u < 4; ++u)
#pragma unroll
      for (int rr = 0; rr < 4; ++rr) {
        int rw = rowBase + t * 16 + q * 4 + rr;
        int cl = colBase + u * 16 + idx;
        float v = acc[t][u][rr];
        out[(size_t)rw * N_NODES + cl] = 1.0f / (1.0f + __expf(-v));
      }
}

extern "C" void kernel_launch(void* const* d_in, const int* in_sizes, int n_in,
                              void* d_out, int out_size, void* d_ws, size_t ws_size,
                              hipStream_t stream) {
  const float* x     = (const float*)d_in[0];
  const int*   ei    = (const int*)d_in[1];
  const int*   batch = (const int*)d_in[2];
  const float* gcn_w = (const float*)d_in[3];
  const float* gcn_b = (const float*)d_in[4];
  const float* lin_w = (const float*)d_in[5];
  const float* lin_b = (const float*)d_in[6];
  const float* dec_w = (const float*)d_in[7];
  const float* dec_b = (const float*)d_in[8];

  float* out     = (float*)d_out;
  float* z_node  = out;                                   // 16384*64
  float* z_graph = out + (size_t)N_NODES * LAT;           // +1024
  float* x_hat   = z_graph + N_GRAPHS * LAT;              // +16384*128
  float* a_hat   = x_hat + (size_t)N_NODES * IN_CH;       // +16384*16384

  float* ws   = (float*)d_ws;
  float* deg  = ws;                                       // 16384
  float* dinv = ws + 16384;                               // 16384
  float* gsum = ws + 32768;                               // 1024
  float* gcnt = ws + 33792;                               // 16 (+pad)
  float* xrow = ws + 33824;                               // 2048 (+pad to 36864)
  float* agg  = ws + 36864;                               // 16384*128
  float* h    = ws + 36864 + (size_t)N_NODES * IN_CH;     // 16384*256
  __bf16* zb  = (__bf16*)(h + (size_t)N_NODES * HID_CH);  // 16384*64 bf16

  const int* erow = ei;             // edge_index[0] = sources
  const int* ecol = ei + N_EDGES;   // edge_index[1] = targets

  k_init<<<64, 256, 0, stream>>>(deg, gsum, gcnt);
  k_deg<<<N_EDGES / 256, 256, 0, stream>>>(ecol, deg);
  k_dinv<<<N_NODES / 256, 256, 0, stream>>>(deg, dinv);
  k_selfinit<<<N_NODES * 32 / 256, 256, 0, stream>>>(x, dinv, agg);
  k_edge_agg<<<N_EDGES * 32 / 256, 256, 0, stream>>>(erow, ecol, x, dinv, agg);
  gemm_nt<true, false><<<dim3(HID_CH / 64, N_NODES / 64), 256, 0, stream>>>(
      agg, gcn_w, gcn_b, h, nullptr, N_NODES, HID_CH, IN_CH);
  gemm_nt<false, true><<<dim3(LAT / 64, N_NODES / 64), 256, 0, stream>>>(
      h, lin_w, lin_b, z_node, zb, N_NODES, LAT, HID_CH);
  k_pool<<<N_NODES / POOL_NODES, 64, 0, stream>>>(z_node, batch, gsum, gcnt);
  k_graph<<<1, 1024, 0, stream>>>(gsum, gcnt, dec_w, dec_b, z_graph, xrow);
  k_xhat<<<N_NODES * 32 / 256, 256, 0, stream>>>(batch, xrow, x_hat);
  k_ahat<<<dim3(N_NODES / 128, N_NODES / 64), 256, 0, stream>>>(zb, a_hat);
}